// Round 4
// baseline (329.000 us; speedup 1.0000x reference)
//
#include <hip/hip_runtime.h>
#include <cstdint>
#include <cstddef>

#define NH 8
#define LQ 2048
#define DH 64
#define NKT_Q 8   // split-k=4: each block does 8 of the 32 k-tiles

typedef __attribute__((ext_vector_type(8))) __bf16 bf16x8;
typedef __attribute__((ext_vector_type(8))) unsigned short ushort8;
typedef __attribute__((ext_vector_type(4))) float floatx4;

__device__ __forceinline__ unsigned short bf_trunc(float x) {
    return (unsigned short)(__float_as_uint(x) >> 16);
}
__device__ __forceinline__ float bf_up(unsigned short h) {
    return __uint_as_float(((unsigned int)h) << 16);
}
__device__ __forceinline__ unsigned short bf_rne(float x) {
    unsigned int u = __float_as_uint(x);
    return (unsigned short)((u + 0x7FFFu + ((u >> 16) & 1u)) >> 16);
}
struct hl_t { unsigned short h, l; };
// x ~= h + l with |x-h-l| <= 2^-16 |x|
__device__ __forceinline__ hl_t split2(float x) {
    hl_t r;
    r.h = bf_trunc(x);
    r.l = bf_trunc(x - bf_up(r.h));
    return r;
}

#define MFMA16(A, B, C) __builtin_amdgcn_mfma_f32_16x16x32_bf16((A), (B), (C), 0, 0, 0)

// Grid: 1024 = 32 qt * 8 h * 4 quarter -> 4 blocks/CU (LDS = 40960B x4 = 160KiB exactly).
// Block: 256 thr (4 waves, 16 q-rows each).
// Writes unnormalized e=exp(s') to probs, PV/l partials to ws.
__global__ __launch_bounds__(256, 4) void attn_main(
    const float* __restrict__ qp,  const float* __restrict__ kp,
    const float* __restrict__ vp,  const float* __restrict__ cp,
    const float* __restrict__ dqp, const float* __restrict__ dktp,
    const float* __restrict__ dkbp,const float* __restrict__ dksp,
    const float* __restrict__ rtp, const float* __restrict__ rbp,
    const float* __restrict__ Wwp, const float* __restrict__ Wbp,
    float* __restrict__ probp, float* __restrict__ lws, float* __restrict__ pvws)
{
    __shared__ unsigned short sh_khi[64 * 72];   // Q-hi staging, then K-hi
    __shared__ unsigned short sh_klo[64 * 72];   // Q-lo staging, then K-lo, then ebf (P tile bf16)
    __shared__ unsigned short sh_vhi[64 * 72];   // V^T hi (c folded in)
    __shared__ unsigned short sh_vlo[64 * 72];   // V^T lo
    __shared__ float sh_meta[64 * 13];
    __shared__ float sh_dqs[64 * 3];

    const int bid  = blockIdx.x;
    const int quar = bid & 3;
    const int h    = (bid >> 2) & 7;
    const int qt   = bid >> 5;          // qt-major for rel L3 locality
    const int q0   = qt * 64;
    const int t    = threadIdx.x;
    const int lane = t & 63;
    const int m    = lane & 15;
    const int quad = lane >> 4;
    const int w16  = (t >> 6) * 16;

    float Ww[4], Wb[4];
#pragma unroll
    for (int f = 0; f < 4; ++f) { Ww[f] = Wwp[f * NH + h]; Wb[f] = Wbp[f * NH + h]; }

    // ---- stage Q (hi/lo, pre-scaled by 1/sqrt(64)) into the K buffers, load dqs ----
    {
        const int row = t >> 2, s = t & 3;
        const float* src = qp + ((size_t)(h * LQ + q0 + row)) * DH + s * 16;
        ushort8 vh0, vh1, vl0, vl1;
#pragma unroll
        for (int j = 0; j < 2; ++j) {
            float4 x = *(const float4*)(src + 4 * j);
            hl_t a = split2(x.x * 0.125f), b = split2(x.y * 0.125f);
            hl_t c = split2(x.z * 0.125f), d = split2(x.w * 0.125f);
            vh0[4 * j + 0] = a.h; vl0[4 * j + 0] = a.l;
            vh0[4 * j + 1] = b.h; vl0[4 * j + 1] = b.l;
            vh0[4 * j + 2] = c.h; vl0[4 * j + 2] = c.l;
            vh0[4 * j + 3] = d.h; vl0[4 * j + 3] = d.l;
        }
#pragma unroll
        for (int j = 0; j < 2; ++j) {
            float4 x = *(const float4*)(src + 8 + 4 * j);
            hl_t a = split2(x.x * 0.125f), b = split2(x.y * 0.125f);
            hl_t c = split2(x.z * 0.125f), d = split2(x.w * 0.125f);
            vh1[4 * j + 0] = a.h; vl1[4 * j + 0] = a.l;
            vh1[4 * j + 1] = b.h; vl1[4 * j + 1] = b.l;
            vh1[4 * j + 2] = c.h; vl1[4 * j + 2] = c.l;
            vh1[4 * j + 3] = d.h; vl1[4 * j + 3] = d.l;
        }
        const int base = row * 72 + s * 16;
        *(ushort8*)&sh_khi[base] = vh0;  *(ushort8*)&sh_khi[base + 8] = vh1;
        *(ushort8*)&sh_klo[base] = vl0;  *(ushort8*)&sh_klo[base + 8] = vl1;
        if (t < 64) {
            sh_dqs[t * 3 + 0] = dqp[(q0 + t) * 3 + 0];
            sh_dqs[t * 3 + 1] = dqp[(q0 + t) * 3 + 1];
            sh_dqs[t * 3 + 2] = dqp[(q0 + t) * 3 + 2];
        }
    }
    __syncthreads();

    // Q A-fragments live in registers for the whole kernel
    bf16x8 aqh[2], aql[2];
#pragma unroll
    for (int kc = 0; kc < 2; ++kc) {
        aqh[kc] = *(const bf16x8*)&sh_khi[(w16 + m) * 72 + kc * 32 + quad * 8];
        aql[kc] = *(const bf16x8*)&sh_klo[(w16 + m) * 72 + kc * 32 + quad * 8];
    }
    float dq0[4], dq1[4], dq2[4];
#pragma unroll
    for (int r = 0; r < 4; ++r) {
        const int row = w16 + quad * 4 + r;
        dq0[r] = sh_dqs[row * 3 + 0]; dq1[r] = sh_dqs[row * 3 + 1]; dq2[r] = sh_dqs[row * 3 + 2];
    }
    __syncthreads();   // Q buffers free for K staging

    const floatx4 zf = {0.f, 0.f, 0.f, 0.f};
    floatx4 pacc[4] = {zf, zf, zf, zf};
    float lpart[4] = {0.f, 0.f, 0.f, 0.f};

    for (int kth = 0; kth < NKT_Q; ++kth) {
        const int k0 = (quar * NKT_Q + kth) * 64;

        // ---- stage K (hi/lo, row-major) ----
        {
            const int row = t >> 2, s = t & 3;
            const float* src = kp + ((size_t)(h * LQ + k0 + row)) * DH + s * 16;
            ushort8 vh0, vh1, vl0, vl1;
#pragma unroll
            for (int j = 0; j < 2; ++j) {
                float4 x = *(const float4*)(src + 4 * j);
                hl_t a = split2(x.x), b = split2(x.y), c = split2(x.z), d = split2(x.w);
                vh0[4 * j + 0] = a.h; vl0[4 * j + 0] = a.l;
                vh0[4 * j + 1] = b.h; vl0[4 * j + 1] = b.l;
                vh0[4 * j + 2] = c.h; vl0[4 * j + 2] = c.l;
                vh0[4 * j + 3] = d.h; vl0[4 * j + 3] = d.l;
            }
#pragma unroll
            for (int j = 0; j < 2; ++j) {
                float4 x = *(const float4*)(src + 8 + 4 * j);
                hl_t a = split2(x.x), b = split2(x.y), c = split2(x.z), d = split2(x.w);
                vh1[4 * j + 0] = a.h; vl1[4 * j + 0] = a.l;
                vh1[4 * j + 1] = b.h; vl1[4 * j + 1] = b.l;
                vh1[4 * j + 2] = c.h; vl1[4 * j + 2] = c.l;
                vh1[4 * j + 3] = d.h; vl1[4 * j + 3] = d.l;
            }
            const int base = row * 72 + s * 16;
            *(ushort8*)&sh_khi[base] = vh0;  *(ushort8*)&sh_khi[base + 8] = vh1;
            *(ushort8*)&sh_klo[base] = vl0;  *(ushort8*)&sh_klo[base + 8] = vl1;
        }
        // ---- stage V transposed (hi/lo), c folded in; packed b32 writes ----
        {
            const int p = t >> 4;    // 0..15 -> kk pair
            const int mm = t & 15;
#pragma unroll
            for (int g = 0; g < 2; ++g) {
                const int kka = 2 * p + 32 * g;
                const float ca = cp[k0 + kka], cb = cp[k0 + kka + 1];
                const float* va = vp + ((size_t)(h * LQ + k0 + kka)) * DH;
                const float* vb = va + DH;
#pragma unroll
                for (int dd = 0; dd < 4; ++dd) {
                    const int d = mm + 16 * dd;
                    hl_t xa = split2(va[d] * ca);
                    hl_t xb = split2(vb[d] * cb);
                    *(unsigned int*)&sh_vhi[d * 72 + kka] = (unsigned int)xa.h | ((unsigned int)xb.h << 16);
                    *(unsigned int*)&sh_vlo[d * 72 + kka] = (unsigned int)xa.l | ((unsigned int)xb.l << 16);
                }
            }
        }
        // ---- per-k folded bias coefficients ----
        if (t < 64) {
            const int kg = k0 + t;
            const float* sc_ = dksp + (size_t)kg * 8;   // [2][4] top then bottom
            const float* tp  = dktp + (size_t)kg * 3;
            const float* bt  = dkbp + (size_t)kg * 3;
            float cw = 0.f, cb2 = 0.f;
#pragma unroll
            for (int f = 0; f < 3; ++f) {
                const float stf = sc_[f], sbf = sc_[4 + f];
                const float A  = stf + sbf;
                const float Bv = tp[f] * stf + bt[f] * sbf;
                sh_meta[t * 13 + f]     = A * Ww[f];
                sh_meta[t * 13 + 4 + f] = A * Wb[f];
                cw  -= Bv * Ww[f];
                cb2 -= Bv * Wb[f];
            }
            sh_meta[t * 13 + 3]  = cw;              sh_meta[t * 13 + 7]  = cb2;
            sh_meta[t * 13 + 8]  = sc_[3] * Ww[3];  sh_meta[t * 13 + 9]  = sc_[7] * Ww[3];
            sh_meta[t * 13 + 10] = sc_[3] * Wb[3];  sh_meta[t * 13 + 11] = sc_[7] * Wb[3];
        }
        __syncthreads();

        // ---- prefetch rel features (hidden behind MFMA phase) ----
        float rt_[4][4], rb_[4][4];
#pragma unroll
        for (int r = 0; r < 4; ++r) {
            const size_t q = (size_t)(q0 + w16 + quad * 4 + r);
#pragma unroll
            for (int nt = 0; nt < 4; ++nt) {
                rt_[nt][r] = rtp[q * LQ + k0 + nt * 16 + m];
                rb_[nt][r] = rbp[q * LQ + k0 + nt * 16 + m];
            }
        }

        // ---- QK^T: 3-term split-bf16 MFMA (scale pre-folded into Q) ----
        floatx4 sc[4] = {zf, zf, zf, zf};
#pragma unroll
        for (int nt = 0; nt < 4; ++nt) {
#pragma unroll
            for (int kc = 0; kc < 2; ++kc) {
                const int kb = (nt * 16 + m) * 72 + kc * 32 + quad * 8;
                bf16x8 bh = *(const bf16x8*)&sh_khi[kb];
                bf16x8 bl = *(const bf16x8*)&sh_klo[kb];
                sc[nt] = MFMA16(aqh[kc], bh, sc[nt]);
                sc[nt] = MFMA16(aql[kc], bh, sc[nt]);
                sc[nt] = MFMA16(aqh[kc], bl, sc[nt]);
            }
        }
        __syncthreads();   // all waves done with K-lo -> reuse as ebf

        // ---- epilogue: gate + bias + exp; probs store; P->LDS (bf16, A-layout rows) ----
        unsigned short* ebf = sh_klo;
#pragma unroll
        for (int nt = 0; nt < 4; ++nt) {
            const int kcol = nt * 16 + m;
            const float m0 = sh_meta[kcol * 13 + 0],  m1 = sh_meta[kcol * 13 + 1];
            const float m2 = sh_meta[kcol * 13 + 2],  m3 = sh_meta[kcol * 13 + 3];
            const float m4 = sh_meta[kcol * 13 + 4],  m5 = sh_meta[kcol * 13 + 5];
            const float m6 = sh_meta[kcol * 13 + 6],  m7 = sh_meta[kcol * 13 + 7];
            const float m8 = sh_meta[kcol * 13 + 8],  m9 = sh_meta[kcol * 13 + 9];
            const float mA = sh_meta[kcol * 13 + 10], mB = sh_meta[kcol * 13 + 11];
#pragma unroll
            for (int r = 0; r < 4; ++r) {
                float ww = fmaf(dq0[r], m0, m3); ww = fmaf(dq1[r], m1, ww); ww = fmaf(dq2[r], m2, ww);
                ww = fmaf(rt_[nt][r], m8, ww);   ww = fmaf(rb_[nt][r], m9, ww);
                float bb = fmaf(dq0[r], m4, m7); bb = fmaf(dq1[r], m5, bb); bb = fmaf(dq2[r], m6, bb);
                bb = fmaf(rt_[nt][r], mA, bb);   bb = fmaf(rb_[nt][r], mB, bb);
                // softplus(ww) = ln(1 + 2^(ww*log2e)); safe for |ww| << 88 (data is O(10))
                const float wg = __logf(1.0f + __builtin_amdgcn_exp2f(ww * 1.44269504f));
                const float sv = fmaf(sc[nt][r], wg, bb);
                // e = exp(sv - 8): constant shift cancels in normalization
                const float e  = __builtin_amdgcn_exp2f(fmaf(sv, 1.44269504f, -11.5415603f));
                lpart[r] += e;
                probp[((size_t)(h * LQ + q0 + w16 + quad * 4 + r)) * LQ + k0 + kcol] = e;
                ebf[(w16 + quad * 4 + r) * 72 + kcol] = bf_rne(e);
            }
        }

        // ---- PV: bf16 P x split-bf16 V (own-wave rows; no barrier needed before reads) ----
        bf16x8 ap0 = *(const bf16x8*)&ebf[(w16 + m) * 72 + quad * 8];
        bf16x8 ap1 = *(const bf16x8*)&ebf[(w16 + m) * 72 + 32 + quad * 8];
#pragma unroll
        for (int nt = 0; nt < 4; ++nt) {
            const int vb = (nt * 16 + m) * 72 + quad * 8;
            bf16x8 bh0 = *(const bf16x8*)&sh_vhi[vb];
            bf16x8 bl0 = *(const bf16x8*)&sh_vlo[vb];
            bf16x8 bh1 = *(const bf16x8*)&sh_vhi[vb + 32];
            bf16x8 bl1 = *(const bf16x8*)&sh_vlo[vb + 32];
            pacc[nt] = MFMA16(ap0, bh0, pacc[nt]);
            pacc[nt] = MFMA16(ap0, bl0, pacc[nt]);
            pacc[nt] = MFMA16(ap1, bh1, pacc[nt]);
            pacc[nt] = MFMA16(ap1, bl1, pacc[nt]);
        }
        __syncthreads();   // ebf/vT consumed before next staging
    }

    // ---- row-sum partials: reduce over the 16 m-lanes ----
#pragma unroll
    for (int off = 1; off < 16; off <<= 1) {
#pragma unroll
        for (int r = 0; r < 4; ++r) lpart[r] += __shfl_xor(lpart[r], off, 64);
    }
    if (m == 0) {
#pragma unroll
        for (int r = 0; r < 4; ++r)
            lws[quar * (NH * LQ) + h * LQ + q0 + w16 + quad * 4 + r] = lpart[r];
    }
    // ---- PV partials to ws ----
#pragma unroll
    for (int nt = 0; nt < 4; ++nt) {
#pragma unroll
        for (int r = 0; r < 4; ++r) {
            const size_t row = (size_t)(h * LQ + q0 + w16 + quad * 4 + r);
            pvws[(size_t)quar * (NH * LQ * DH) + row * DH + nt * 16 + m] = pacc[nt][r];
        }
    }
}

// out = (pv0+pv1+pv2+pv3) / (l0+l1+l2+l3)
__global__ void combine_kernel(const float* __restrict__ pvws, const float* __restrict__ lws,
                               float* __restrict__ outp)
{
    const int idx4 = blockIdx.x * 256 + threadIdx.x;   // 0..262143
    const int row  = idx4 >> 4;
    const int d4   = (idx4 & 15) * 4;
    const size_t stride = (size_t)NH * LQ * DH;
    floatx4 s = {0.f, 0.f, 0.f, 0.f};
    float l = 0.f;
#pragma unroll
    for (int qr = 0; qr < 4; ++qr) {
        s += *(const floatx4*)(pvws + qr * stride + (size_t)row * DH + d4);
        l += lws[qr * (NH * LQ) + row];
    }
    const float rl = 1.0f / l;
    *(floatx4*)(outp + (size_t)row * DH + d4) = s * rl;
}

// probs[row][k] = e[row][k] * c[k] / l[row]; 4 rows/block for ILP, nontemporal final store
__global__ __launch_bounds__(256) void norm_kernel(float* __restrict__ probp,
                                                   const float* __restrict__ cp,
                                                   const float* __restrict__ lws)
{
    const int r0 = blockIdx.x * 4;                 // 4096 blocks
    const int t  = threadIdx.x;
    const floatx4 c0 = *(const floatx4*)(cp + t * 4);
    const floatx4 c1 = *(const floatx4*)(cp + (t + 256) * 4);
#pragma unroll
    for (int r = 0; r < 4; ++r) {
        const int row = r0 + r;
        float l = 0.f;
#pragma unroll
        for (int qr = 0; qr < 4; ++qr) l += lws[qr * (NH * LQ) + row];
        const float rl = 1.0f / l;
        float* p = probp + (size_t)row * LQ;
        floatx4 x0 = *(const floatx4*)(p + t * 4);
        floatx4 x1 = *(const floatx4*)(p + (t + 256) * 4);
        x0 = x0 * c0 * rl;
        x1 = x1 * c1 * rl;
        __builtin_nontemporal_store(x0, (floatx4*)(p + t * 4));
        __builtin_nontemporal_store(x1, (floatx4*)(p + (t + 256) * 4));
    }
}

extern "C" void kernel_launch(void* const* d_in, const int* in_sizes, int n_in,
                              void* d_out, int out_size, void* d_ws, size_t ws_size,
                              hipStream_t stream)
{
    (void)in_sizes; (void)n_in; (void)ws_size; (void)out_size;
    const float* qp   = (const float*)d_in[0];
    const float* kp   = (const float*)d_in[1];
    const float* vp   = (const float*)d_in[2];
    const float* cp   = (const float*)d_in[3];
    const float* dqp  = (const float*)d_in[4];
    const float* dktp = (const float*)d_in[5];
    const float* dkbp = (const float*)d_in[6];
    const float* dksp = (const float*)d_in[7];
    const float* rtp  = (const float*)d_in[8];
    const float* rbp  = (const float*)d_in[9];
    const float* Wwp  = (const float*)d_in[10];
    const float* Wbp  = (const float*)d_in[11];

    float* outp  = (float*)d_out;                            // [1,8,2048,64]
    float* probp = (float*)d_out + (size_t)NH * LQ * DH;     // [1,8,2048,2048]

    float* lws  = (float*)d_ws;                              // [4][16384]
    float* pvws = (float*)d_ws + 4 * (NH * LQ);              // [4][16384*64]  (~17 MB total)

    attn_main<<<dim3(1024), dim3(256), 0, stream>>>(
        qp, kp, vp, cp, dqp, dktp, dkbp, dksp, rtp, rbp, Wwp, Wbp, probp, lws, pvws);
    combine_kernel<<<dim3(1024), dim3(256), 0, stream>>>(pvws, lws, outp);
    norm_kernel<<<dim3(4096), dim3(256), 0, stream>>>(probp, cp, lws);
}

// Round 5
// 322.244 us; speedup vs baseline: 1.0210x; 1.0210x over previous
//
#include <hip/hip_runtime.h>
#include <cstdint>
#include <cstddef>

#define NH 8
#define LQ 2048
#define DH 64
#define NKT_Q 8   // split-k=4: each block does 8 of the 32 k-tiles

typedef __attribute__((ext_vector_type(8))) __bf16 bf16x8;
typedef __attribute__((ext_vector_type(8))) unsigned short ushort8;
typedef __attribute__((ext_vector_type(4))) float floatx4;

__device__ __forceinline__ unsigned short bf_trunc(float x) {
    return (unsigned short)(__float_as_uint(x) >> 16);
}
__device__ __forceinline__ float bf_up(unsigned short h) {
    return __uint_as_float(((unsigned int)h) << 16);
}
__device__ __forceinline__ unsigned short bf_rne(float x) {
    unsigned int u = __float_as_uint(x);
    return (unsigned short)((u + 0x7FFFu + ((u >> 16) & 1u)) >> 16);
}
struct hl_t { unsigned short h, l; };
// x ~= h + l with |x-h-l| <= 2^-16 |x|
__device__ __forceinline__ hl_t split2(float x) {
    hl_t r;
    r.h = bf_trunc(x);
    r.l = bf_trunc(x - bf_up(r.h));
    return r;
}

#define MFMA16(A, B, C) __builtin_amdgcn_mfma_f32_16x16x32_bf16((A), (B), (C), 0, 0, 0)

// Grid: 1024 = 32 qt * 8 h * 4 quarter. Block: 256 thr (4 waves, 16 q-rows each).
// launch_bounds min-waves=3: (256,4) forced VGPR to 64 and spilled (R4: +34MB
// FETCH/WRITE scratch traffic, dur 112->152us). At 84 VGPR, 4 blocks/CU still fits.
// FAST=1: store e as bf16 to ews (64MB) and skip the f32 probs store (finalize expands).
// FAST=0: store f32 e to probs (norm_kernel path) — used when ws is too small.
template <bool FAST>
__global__ __launch_bounds__(256, 3) void attn_main(
    const float* __restrict__ qp,  const float* __restrict__ kp,
    const float* __restrict__ vp,  const float* __restrict__ cp,
    const float* __restrict__ dqp, const float* __restrict__ dktp,
    const float* __restrict__ dkbp,const float* __restrict__ dksp,
    const float* __restrict__ rtp, const float* __restrict__ rbp,
    const float* __restrict__ Wwp, const float* __restrict__ Wbp,
    float* __restrict__ probp, float* __restrict__ lws, float* __restrict__ pvws,
    unsigned short* __restrict__ ews)
{
    __shared__ unsigned short sh_khi[64 * 72];   // Q-hi staging, then K-hi
    __shared__ unsigned short sh_klo[64 * 72];   // Q-lo staging, then K-lo, then ebf (P tile bf16)
    __shared__ unsigned short sh_vhi[64 * 72];   // V^T hi (c folded in)
    __shared__ unsigned short sh_vlo[64 * 72];   // V^T lo
    __shared__ float sh_meta[64 * 13];
    __shared__ float sh_dqs[64 * 3];

    const int bid  = blockIdx.x;
    const int quar = bid & 3;
    const int h    = (bid >> 2) & 7;
    const int qt   = bid >> 5;          // qt-major: same-qt blocks co-resident -> rel L2/L3 hits
    const int q0   = qt * 64;
    const int t    = threadIdx.x;
    const int lane = t & 63;
    const int m    = lane & 15;
    const int quad = lane >> 4;
    const int w16  = (t >> 6) * 16;

    float Ww[4], Wb[4];
#pragma unroll
    for (int f = 0; f < 4; ++f) { Ww[f] = Wwp[f * NH + h]; Wb[f] = Wbp[f * NH + h]; }

    // ---- stage Q (hi/lo, pre-scaled by 1/sqrt(64)) into the K buffers, load dqs ----
    {
        const int row = t >> 2, s = t & 3;
        const float* src = qp + ((size_t)(h * LQ + q0 + row)) * DH + s * 16;
        ushort8 vh0, vh1, vl0, vl1;
#pragma unroll
        for (int j = 0; j < 2; ++j) {
            float4 x = *(const float4*)(src + 4 * j);
            hl_t a = split2(x.x * 0.125f), b = split2(x.y * 0.125f);
            hl_t c = split2(x.z * 0.125f), d = split2(x.w * 0.125f);
            vh0[4 * j + 0] = a.h; vl0[4 * j + 0] = a.l;
            vh0[4 * j + 1] = b.h; vl0[4 * j + 1] = b.l;
            vh0[4 * j + 2] = c.h; vl0[4 * j + 2] = c.l;
            vh0[4 * j + 3] = d.h; vl0[4 * j + 3] = d.l;
        }
#pragma unroll
        for (int j = 0; j < 2; ++j) {
            float4 x = *(const float4*)(src + 8 + 4 * j);
            hl_t a = split2(x.x * 0.125f), b = split2(x.y * 0.125f);
            hl_t c = split2(x.z * 0.125f), d = split2(x.w * 0.125f);
            vh1[4 * j + 0] = a.h; vl1[4 * j + 0] = a.l;
            vh1[4 * j + 1] = b.h; vl1[4 * j + 1] = b.l;
            vh1[4 * j + 2] = c.h; vl1[4 * j + 2] = c.l;
            vh1[4 * j + 3] = d.h; vl1[4 * j + 3] = d.l;
        }
        const int base = row * 72 + s * 16;
        *(ushort8*)&sh_khi[base] = vh0;  *(ushort8*)&sh_khi[base + 8] = vh1;
        *(ushort8*)&sh_klo[base] = vl0;  *(ushort8*)&sh_klo[base + 8] = vl1;
        if (t < 64) {
            sh_dqs[t * 3 + 0] = dqp[(q0 + t) * 3 + 0];
            sh_dqs[t * 3 + 1] = dqp[(q0 + t) * 3 + 1];
            sh_dqs[t * 3 + 2] = dqp[(q0 + t) * 3 + 2];
        }
    }
    __syncthreads();

    // Q A-fragments live in registers for the whole kernel
    bf16x8 aqh[2], aql[2];
#pragma unroll
    for (int kc = 0; kc < 2; ++kc) {
        aqh[kc] = *(const bf16x8*)&sh_khi[(w16 + m) * 72 + kc * 32 + quad * 8];
        aql[kc] = *(const bf16x8*)&sh_klo[(w16 + m) * 72 + kc * 32 + quad * 8];
    }
    float dq0[4], dq1[4], dq2[4];
#pragma unroll
    for (int r = 0; r < 4; ++r) {
        const int row = w16 + quad * 4 + r;
        dq0[r] = sh_dqs[row * 3 + 0]; dq1[r] = sh_dqs[row * 3 + 1]; dq2[r] = sh_dqs[row * 3 + 2];
    }
    __syncthreads();   // Q buffers free for K staging

    const floatx4 zf = {0.f, 0.f, 0.f, 0.f};
    floatx4 pacc[4] = {zf, zf, zf, zf};
    float lpart[4] = {0.f, 0.f, 0.f, 0.f};

    for (int kth = 0; kth < NKT_Q; ++kth) {
        const int k0 = (quar * NKT_Q + kth) * 64;

        // ---- stage K (hi/lo, row-major) ----
        {
            const int row = t >> 2, s = t & 3;
            const float* src = kp + ((size_t)(h * LQ + k0 + row)) * DH + s * 16;
            ushort8 vh0, vh1, vl0, vl1;
#pragma unroll
            for (int j = 0; j < 2; ++j) {
                float4 x = *(const float4*)(src + 4 * j);
                hl_t a = split2(x.x), b = split2(x.y), c = split2(x.z), d = split2(x.w);
                vh0[4 * j + 0] = a.h; vl0[4 * j + 0] = a.l;
                vh0[4 * j + 1] = b.h; vl0[4 * j + 1] = b.l;
                vh0[4 * j + 2] = c.h; vl0[4 * j + 2] = c.l;
                vh0[4 * j + 3] = d.h; vl0[4 * j + 3] = d.l;
            }
#pragma unroll
            for (int j = 0; j < 2; ++j) {
                float4 x = *(const float4*)(src + 8 + 4 * j);
                hl_t a = split2(x.x), b = split2(x.y), c = split2(x.z), d = split2(x.w);
                vh1[4 * j + 0] = a.h; vl1[4 * j + 0] = a.l;
                vh1[4 * j + 1] = b.h; vl1[4 * j + 1] = b.l;
                vh1[4 * j + 2] = c.h; vl1[4 * j + 2] = c.l;
                vh1[4 * j + 3] = d.h; vl1[4 * j + 3] = d.l;
            }
            const int base = row * 72 + s * 16;
            *(ushort8*)&sh_khi[base] = vh0;  *(ushort8*)&sh_khi[base + 8] = vh1;
            *(ushort8*)&sh_klo[base] = vl0;  *(ushort8*)&sh_klo[base + 8] = vl1;
        }
        // ---- stage V transposed (hi/lo), c folded in; packed b32 writes ----
        {
            const int p = t >> 4;    // 0..15 -> kk pair
            const int mm = t & 15;
#pragma unroll
            for (int g = 0; g < 2; ++g) {
                const int kka = 2 * p + 32 * g;
                const float ca = cp[k0 + kka], cb = cp[k0 + kka + 1];
                const float* va = vp + ((size_t)(h * LQ + k0 + kka)) * DH;
                const float* vb = va + DH;
#pragma unroll
                for (int dd = 0; dd < 4; ++dd) {
                    const int d = mm + 16 * dd;
                    hl_t xa = split2(va[d] * ca);
                    hl_t xb = split2(vb[d] * cb);
                    *(unsigned int*)&sh_vhi[d * 72 + kka] = (unsigned int)xa.h | ((unsigned int)xb.h << 16);
                    *(unsigned int*)&sh_vlo[d * 72 + kka] = (unsigned int)xa.l | ((unsigned int)xb.l << 16);
                }
            }
        }
        // ---- per-k folded bias coefficients ----
        if (t < 64) {
            const int kg = k0 + t;
            const float* sc_ = dksp + (size_t)kg * 8;   // [2][4] top then bottom
            const float* tp  = dktp + (size_t)kg * 3;
            const float* bt  = dkbp + (size_t)kg * 3;
            float cw = 0.f, cb2 = 0.f;
#pragma unroll
            for (int f = 0; f < 3; ++f) {
                const float stf = sc_[f], sbf = sc_[4 + f];
                const float A  = stf + sbf;
                const float Bv = tp[f] * stf + bt[f] * sbf;
                sh_meta[t * 13 + f]     = A * Ww[f];
                sh_meta[t * 13 + 4 + f] = A * Wb[f];
                cw  -= Bv * Ww[f];
                cb2 -= Bv * Wb[f];
            }
            sh_meta[t * 13 + 3]  = cw;              sh_meta[t * 13 + 7]  = cb2;
            sh_meta[t * 13 + 8]  = sc_[3] * Ww[3];  sh_meta[t * 13 + 9]  = sc_[7] * Ww[3];
            sh_meta[t * 13 + 10] = sc_[3] * Wb[3];  sh_meta[t * 13 + 11] = sc_[7] * Wb[3];
        }
        __syncthreads();

        // ---- prefetch rel features (hidden behind MFMA phase) ----
        float rt_[4][4], rb_[4][4];
#pragma unroll
        for (int r = 0; r < 4; ++r) {
            const size_t q = (size_t)(q0 + w16 + quad * 4 + r);
#pragma unroll
            for (int nt = 0; nt < 4; ++nt) {
                rt_[nt][r] = rtp[q * LQ + k0 + nt * 16 + m];
                rb_[nt][r] = rbp[q * LQ + k0 + nt * 16 + m];
            }
        }

        // ---- QK^T: 3-term split-bf16 MFMA (scale pre-folded into Q) ----
        floatx4 sc[4] = {zf, zf, zf, zf};
#pragma unroll
        for (int nt = 0; nt < 4; ++nt) {
#pragma unroll
            for (int kc = 0; kc < 2; ++kc) {
                const int kb = (nt * 16 + m) * 72 + kc * 32 + quad * 8;
                bf16x8 bh = *(const bf16x8*)&sh_khi[kb];
                bf16x8 bl = *(const bf16x8*)&sh_klo[kb];
                sc[nt] = MFMA16(aqh[kc], bh, sc[nt]);
                sc[nt] = MFMA16(aql[kc], bh, sc[nt]);
                sc[nt] = MFMA16(aqh[kc], bl, sc[nt]);
            }
        }
        __syncthreads();   // all waves done with K-lo -> reuse as ebf

        // ---- epilogue: gate + bias + exp; P->LDS (bf16, A-layout rows) ----
        unsigned short* ebf = sh_klo;
#pragma unroll
        for (int nt = 0; nt < 4; ++nt) {
            const int kcol = nt * 16 + m;
            const float m0 = sh_meta[kcol * 13 + 0],  m1 = sh_meta[kcol * 13 + 1];
            const float m2 = sh_meta[kcol * 13 + 2],  m3 = sh_meta[kcol * 13 + 3];
            const float m4 = sh_meta[kcol * 13 + 4],  m5 = sh_meta[kcol * 13 + 5];
            const float m6 = sh_meta[kcol * 13 + 6],  m7 = sh_meta[kcol * 13 + 7];
            const float m8 = sh_meta[kcol * 13 + 8],  m9 = sh_meta[kcol * 13 + 9];
            const float mA = sh_meta[kcol * 13 + 10], mB = sh_meta[kcol * 13 + 11];
#pragma unroll
            for (int r = 0; r < 4; ++r) {
                float ww = fmaf(dq0[r], m0, m3); ww = fmaf(dq1[r], m1, ww); ww = fmaf(dq2[r], m2, ww);
                ww = fmaf(rt_[nt][r], m8, ww);   ww = fmaf(rb_[nt][r], m9, ww);
                float bb = fmaf(dq0[r], m4, m7); bb = fmaf(dq1[r], m5, bb); bb = fmaf(dq2[r], m6, bb);
                bb = fmaf(rt_[nt][r], mA, bb);   bb = fmaf(rb_[nt][r], mB, bb);
                // softplus(ww) = ln(1 + 2^(ww*log2e)); safe for |ww| << 88 (data is O(10))
                const float wg = __logf(1.0f + __builtin_amdgcn_exp2f(ww * 1.44269504f));
                const float sv = fmaf(sc[nt][r], wg, bb);
                // e = exp(sv - 8): constant shift cancels in normalization
                const float e  = __builtin_amdgcn_exp2f(fmaf(sv, 1.44269504f, -11.5415603f));
                lpart[r] += e;
                if (!FAST)
                    probp[((size_t)(h * LQ + q0 + w16 + quad * 4 + r)) * LQ + k0 + kcol] = e;
                ebf[(w16 + quad * 4 + r) * 72 + kcol] = bf_rne(e);
            }
        }

        // ---- PV: bf16 P x split-bf16 V (own-wave rows; no barrier needed before reads) ----
        bf16x8 ap0 = *(const bf16x8*)&ebf[(w16 + m) * 72 + quad * 8];
        bf16x8 ap1 = *(const bf16x8*)&ebf[(w16 + m) * 72 + 32 + quad * 8];
#pragma unroll
        for (int nt = 0; nt < 4; ++nt) {
            const int vb = (nt * 16 + m) * 72 + quad * 8;
            bf16x8 bh0 = *(const bf16x8*)&sh_vhi[vb];
            bf16x8 bl0 = *(const bf16x8*)&sh_vlo[vb];
            bf16x8 bh1 = *(const bf16x8*)&sh_vhi[vb + 32];
            bf16x8 bl1 = *(const bf16x8*)&sh_vlo[vb + 32];
            pacc[nt] = MFMA16(ap0, bh0, pacc[nt]);
            pacc[nt] = MFMA16(ap0, bl0, pacc[nt]);
            pacc[nt] = MFMA16(ap1, bh1, pacc[nt]);
            pacc[nt] = MFMA16(ap1, bl1, pacc[nt]);
        }

        // ---- FAST: dump own-wave ebf rows to global as bf16 (coalesced b128) ----
        if (FAST) {
            const int rrow = w16 + (lane >> 2);   // 16 rows/wave, 4 lanes per row
#pragma unroll
            for (int it = 0; it < 2; ++it) {
                const int cc = (lane & 3) + it * 4;  // 8 x ushort8 per 64-col row
                ushort8 v = *(const ushort8*)&ebf[rrow * 72 + cc * 8];
                *(ushort8*)(ews + ((size_t)(h * LQ + q0 + rrow)) * LQ + k0 + cc * 8) = v;
            }
        }
        __syncthreads();   // ebf/vT consumed before next staging
    }

    // ---- row-sum partials: reduce over the 16 m-lanes ----
#pragma unroll
    for (int off = 1; off < 16; off <<= 1) {
#pragma unroll
        for (int r = 0; r < 4; ++r) lpart[r] += __shfl_xor(lpart[r], off, 64);
    }
    if (m == 0) {
#pragma unroll
        for (int r = 0; r < 4; ++r)
            lws[quar * (NH * LQ) + h * LQ + q0 + w16 + quad * 4 + r] = lpart[r];
    }
    // ---- PV partials to ws ----
#pragma unroll
    for (int nt = 0; nt < 4; ++nt) {
#pragma unroll
        for (int r = 0; r < 4; ++r) {
            const size_t row = (size_t)(h * LQ + q0 + w16 + quad * 4 + r);
            pvws[(size_t)quar * (NH * LQ * DH) + row * DH + nt * 16 + m] = pacc[nt][r];
        }
    }
}

// out = (pv0+pv1+pv2+pv3) / (l0+l1+l2+l3)
__global__ void combine_kernel(const float* __restrict__ pvws, const float* __restrict__ lws,
                               float* __restrict__ outp)
{
    const int idx4 = blockIdx.x * 256 + threadIdx.x;   // 0..262143
    const int row  = idx4 >> 4;
    const int d4   = (idx4 & 15) * 4;
    const size_t stride = (size_t)NH * LQ * DH;
    floatx4 s = {0.f, 0.f, 0.f, 0.f};
    float l = 0.f;
#pragma unroll
    for (int qr = 0; qr < 4; ++qr) {
        s += *(const floatx4*)(pvws + qr * stride + (size_t)row * DH + d4);
        l += lws[qr * (NH * LQ) + row];
    }
    const float rl = 1.0f / l;
    *(floatx4*)(outp + (size_t)row * DH + d4) = s * rl;
}

// FAST path: probs[row][k] = bf16(e)[row][k] * c[k] / l[row]. Pure streaming expand:
// read 64MB bf16, write 128MB f32 (vs 128+128+128 RMW of the norm path).
__global__ __launch_bounds__(256) void finalize_kernel(const unsigned short* __restrict__ ews,
                                                       const float* __restrict__ cp,
                                                       const float* __restrict__ lws,
                                                       float* __restrict__ probp)
{
    const int gid = blockIdx.x * 256 + threadIdx.x;    // 16384 rows x 256 chunks
    const int row = gid >> 8;
    const int k   = (gid & 255) * 8;
    float l = 0.f;
#pragma unroll
    for (int qr = 0; qr < 4; ++qr) l += lws[qr * (NH * LQ) + row];
    const float rl = 1.0f / l;
    const ushort8 e = *(const ushort8*)(ews + (size_t)row * LQ + k);
    const floatx4 c0 = *(const floatx4*)(cp + k);
    const floatx4 c1 = *(const floatx4*)(cp + k + 4);
    floatx4 o0, o1;
#pragma unroll
    for (int j = 0; j < 4; ++j) o0[j] = bf_up(e[j]) * c0[j] * rl;
#pragma unroll
    for (int j = 0; j < 4; ++j) o1[j] = bf_up(e[4 + j]) * c1[j] * rl;
    __builtin_nontemporal_store(o0, (floatx4*)(probp + (size_t)row * LQ + k));
    __builtin_nontemporal_store(o1, (floatx4*)(probp + (size_t)row * LQ + k + 4));
}

// Fallback: probs RMW in place (e stored f32 by attn_main<false>)
__global__ __launch_bounds__(256) void norm_kernel(float* __restrict__ probp,
                                                   const float* __restrict__ cp,
                                                   const float* __restrict__ lws)
{
    const int r0 = blockIdx.x * 4;
    const int t  = threadIdx.x;
    const floatx4 c0 = *(const floatx4*)(cp + t * 4);
    const floatx4 c1 = *(const floatx4*)(cp + (t + 256) * 4);
#pragma unroll
    for (int r = 0; r < 4; ++r) {
        const int row = r0 + r;
        float l = 0.f;
#pragma unroll
        for (int qr = 0; qr < 4; ++qr) l += lws[qr * (NH * LQ) + row];
        const float rl = 1.0f / l;
        float* p = probp + (size_t)row * LQ;
        floatx4 x0 = *(const floatx4*)(p + t * 4);
        floatx4 x1 = *(const floatx4*)(p + (t + 256) * 4);
        x0 = x0 * c0 * rl;
        x1 = x1 * c1 * rl;
        __builtin_nontemporal_store(x0, (floatx4*)(p + t * 4));
        __builtin_nontemporal_store(x1, (floatx4*)(p + (t + 256) * 4));
    }
}

extern "C" void kernel_launch(void* const* d_in, const int* in_sizes, int n_in,
                              void* d_out, int out_size, void* d_ws, size_t ws_size,
                              hipStream_t stream)
{
    (void)in_sizes; (void)n_in; (void)out_size;
    const float* qp   = (const float*)d_in[0];
    const float* kp   = (const float*)d_in[1];
    const float* vp   = (const float*)d_in[2];
    const float* cp   = (const float*)d_in[3];
    const float* dqp  = (const float*)d_in[4];
    const float* dktp = (const float*)d_in[5];
    const float* dkbp = (const float*)d_in[6];
    const float* dksp = (const float*)d_in[7];
    const float* rtp  = (const float*)d_in[8];
    const float* rbp  = (const float*)d_in[9];
    const float* Wwp  = (const float*)d_in[10];
    const float* Wbp  = (const float*)d_in[11];

    float* outp  = (float*)d_out;                            // [1,8,2048,64]
    float* probp = (float*)d_out + (size_t)NH * LQ * DH;     // [1,8,2048,2048]

    float* lws  = (float*)d_ws;                              // [4][16384]        = 256 KB
    float* pvws = (float*)d_ws + 4 * (NH * LQ);              // [4][16384*64] f32 = 16 MB
    unsigned short* ews = (unsigned short*)(pvws + (size_t)4 * NH * LQ * DH);  // 64 MB bf16

    const size_t need = (size_t)4 * NH * LQ * 4
                      + (size_t)4 * NH * LQ * DH * 4
                      + (size_t)NH * LQ * LQ * 2;
    const bool fast = ws_size >= need;

    if (fast) {
        attn_main<true><<<dim3(1024), dim3(256), 0, stream>>>(
            qp, kp, vp, cp, dqp, dktp, dkbp, dksp, rtp, rbp, Wwp, Wbp, probp, lws, pvws, ews);
        combine_kernel<<<dim3(1024), dim3(256), 0, stream>>>(pvws, lws, outp);
        finalize_kernel<<<dim3(16384), dim3(256), 0, stream>>>(ews, cp, lws, probp);
    } else {
        attn_main<false><<<dim3(1024), dim3(256), 0, stream>>>(
            qp, kp, vp, cp, dqp, dktp, dkbp, dksp, rtp, rbp, Wwp, Wbp, probp, lws, pvws, ews);
        combine_kernel<<<dim3(1024), dim3(256), 0, stream>>>(pvws, lws, outp);
        norm_kernel<<<dim3(4096), dim3(256), 0, stream>>>(probp, cp, lws);
    }
}

// Round 6
// 307.246 us; speedup vs baseline: 1.0708x; 1.0488x over previous
//
#include <hip/hip_runtime.h>
#include <cstdint>
#include <cstddef>

#define NH 8
#define LQ 2048
#define DH 64
#define NKT_Q 8   // split-k=4: each block does 8 of the 32 k-tiles

typedef __attribute__((ext_vector_type(8))) __bf16 bf16x8;
typedef __attribute__((ext_vector_type(8))) unsigned short ushort8;
typedef __attribute__((ext_vector_type(4))) unsigned short ushort4v;
typedef __attribute__((ext_vector_type(4))) float floatx4;

__device__ __forceinline__ unsigned short bf_trunc(float x) {
    return (unsigned short)(__float_as_uint(x) >> 16);
}
__device__ __forceinline__ float bf_up(unsigned short h) {
    return __uint_as_float(((unsigned int)h) << 16);
}
__device__ __forceinline__ unsigned short bf_rne(float x) {
    unsigned int u = __float_as_uint(x);
    return (unsigned short)((u + 0x7FFFu + ((u >> 16) & 1u)) >> 16);
}
struct hl_t { unsigned short h, l; };
// x ~= h + l with |x-h-l| <= 2^-16 |x|
__device__ __forceinline__ hl_t split2(float x) {
    hl_t r;
    r.h = bf_trunc(x);
    r.l = bf_trunc(x - bf_up(r.h));
    return r;
}

#define MFMA16(A, B, C) __builtin_amdgcn_mfma_f32_16x16x32_bf16((A), (B), (C), 0, 0, 0)

// Grid: 1024 = 32 qt * 8 h * 4 quarter. Block: 256 thr (4 waves, 16 q-rows each).
// launch_bounds min-waves=3: (256,4) forced VGPR to 64 and spilled (R4).
// V is staged as single RNE bf16 (no lo term): out error from bf16-V matches the
// already-present bf16-P error (~2^-9 weighted avg), measured headroom 3x.
// FAST=1: store e as bf16 to ews and skip the f32 probs store (finalize expands).
template <bool FAST>
__global__ __launch_bounds__(256, 3) void attn_main(
    const float* __restrict__ qp,  const float* __restrict__ kp,
    const float* __restrict__ vp,  const float* __restrict__ cp,
    const float* __restrict__ dqp, const float* __restrict__ dktp,
    const float* __restrict__ dkbp,const float* __restrict__ dksp,
    const float* __restrict__ rtp, const float* __restrict__ rbp,
    const float* __restrict__ Wwp, const float* __restrict__ Wbp,
    float* __restrict__ probp, float* __restrict__ lws, float* __restrict__ pvws,
    unsigned short* __restrict__ ews)
{
    __shared__ unsigned short sh_khi[64 * 72];   // Q-hi staging, then K-hi
    __shared__ unsigned short sh_klo[64 * 72];   // Q-lo staging, then K-lo, then ebf (P tile bf16)
    __shared__ unsigned short sh_vhi[64 * 72];   // V^T bf16-RNE (c folded in)
    __shared__ float sh_meta[64 * 13];
    __shared__ float sh_dqs[64 * 3];

    const int bid  = blockIdx.x;
    const int quar = bid & 3;
    const int h    = (bid >> 2) & 7;
    const int qt   = bid >> 5;          // qt-major: same-qt blocks co-resident -> rel L2/L3 hits
    const int q0   = qt * 64;
    const int t    = threadIdx.x;
    const int lane = t & 63;
    const int m    = lane & 15;
    const int quad = lane >> 4;
    const int w16  = (t >> 6) * 16;

    float Ww[4], Wb[4];
#pragma unroll
    for (int f = 0; f < 4; ++f) { Ww[f] = Wwp[f * NH + h]; Wb[f] = Wbp[f * NH + h]; }

    // ---- stage Q (hi/lo, pre-scaled by 1/sqrt(64)) into the K buffers, load dqs ----
    {
        const int row = t >> 2, s = t & 3;
        const float* src = qp + ((size_t)(h * LQ + q0 + row)) * DH + s * 16;
        ushort8 vh0, vh1, vl0, vl1;
#pragma unroll
        for (int j = 0; j < 2; ++j) {
            float4 x = *(const float4*)(src + 4 * j);
            hl_t a = split2(x.x * 0.125f), b = split2(x.y * 0.125f);
            hl_t c = split2(x.z * 0.125f), d = split2(x.w * 0.125f);
            vh0[4 * j + 0] = a.h; vl0[4 * j + 0] = a.l;
            vh0[4 * j + 1] = b.h; vl0[4 * j + 1] = b.l;
            vh0[4 * j + 2] = c.h; vl0[4 * j + 2] = c.l;
            vh0[4 * j + 3] = d.h; vl0[4 * j + 3] = d.l;
        }
#pragma unroll
        for (int j = 0; j < 2; ++j) {
            float4 x = *(const float4*)(src + 8 + 4 * j);
            hl_t a = split2(x.x * 0.125f), b = split2(x.y * 0.125f);
            hl_t c = split2(x.z * 0.125f), d = split2(x.w * 0.125f);
            vh1[4 * j + 0] = a.h; vl1[4 * j + 0] = a.l;
            vh1[4 * j + 1] = b.h; vl1[4 * j + 1] = b.l;
            vh1[4 * j + 2] = c.h; vl1[4 * j + 2] = c.l;
            vh1[4 * j + 3] = d.h; vl1[4 * j + 3] = d.l;
        }
        const int base = row * 72 + s * 16;
        *(ushort8*)&sh_khi[base] = vh0;  *(ushort8*)&sh_khi[base + 8] = vh1;
        *(ushort8*)&sh_klo[base] = vl0;  *(ushort8*)&sh_klo[base + 8] = vl1;
        if (t < 64) {
            sh_dqs[t * 3 + 0] = dqp[(q0 + t) * 3 + 0];
            sh_dqs[t * 3 + 1] = dqp[(q0 + t) * 3 + 1];
            sh_dqs[t * 3 + 2] = dqp[(q0 + t) * 3 + 2];
        }
    }
    __syncthreads();

    // Q A-fragments live in registers for the whole kernel
    bf16x8 aqh[2], aql[2];
#pragma unroll
    for (int kc = 0; kc < 2; ++kc) {
        aqh[kc] = *(const bf16x8*)&sh_khi[(w16 + m) * 72 + kc * 32 + quad * 8];
        aql[kc] = *(const bf16x8*)&sh_klo[(w16 + m) * 72 + kc * 32 + quad * 8];
    }
    float dq0[4], dq1[4], dq2[4];
#pragma unroll
    for (int r = 0; r < 4; ++r) {
        const int row = w16 + quad * 4 + r;
        dq0[r] = sh_dqs[row * 3 + 0]; dq1[r] = sh_dqs[row * 3 + 1]; dq2[r] = sh_dqs[row * 3 + 2];
    }
    __syncthreads();   // Q buffers free for K staging

    const floatx4 zf = {0.f, 0.f, 0.f, 0.f};
    floatx4 pacc[4] = {zf, zf, zf, zf};
    float lpart[4] = {0.f, 0.f, 0.f, 0.f};

    for (int kth = 0; kth < NKT_Q; ++kth) {
        const int k0 = (quar * NKT_Q + kth) * 64;

        // ---- stage K (hi/lo, row-major) ----
        {
            const int row = t >> 2, s = t & 3;
            const float* src = kp + ((size_t)(h * LQ + k0 + row)) * DH + s * 16;
            ushort8 vh0, vh1, vl0, vl1;
#pragma unroll
            for (int j = 0; j < 2; ++j) {
                float4 x = *(const float4*)(src + 4 * j);
                hl_t a = split2(x.x), b = split2(x.y), c = split2(x.z), d = split2(x.w);
                vh0[4 * j + 0] = a.h; vl0[4 * j + 0] = a.l;
                vh0[4 * j + 1] = b.h; vl0[4 * j + 1] = b.l;
                vh0[4 * j + 2] = c.h; vl0[4 * j + 2] = c.l;
                vh0[4 * j + 3] = d.h; vl0[4 * j + 3] = d.l;
            }
#pragma unroll
            for (int j = 0; j < 2; ++j) {
                float4 x = *(const float4*)(src + 8 + 4 * j);
                hl_t a = split2(x.x), b = split2(x.y), c = split2(x.z), d = split2(x.w);
                vh1[4 * j + 0] = a.h; vl1[4 * j + 0] = a.l;
                vh1[4 * j + 1] = b.h; vl1[4 * j + 1] = b.l;
                vh1[4 * j + 2] = c.h; vl1[4 * j + 2] = c.l;
                vh1[4 * j + 3] = d.h; vl1[4 * j + 3] = d.l;
            }
            const int base = row * 72 + s * 16;
            *(ushort8*)&sh_khi[base] = vh0;  *(ushort8*)&sh_khi[base + 8] = vh1;
            *(ushort8*)&sh_klo[base] = vl0;  *(ushort8*)&sh_klo[base + 8] = vl1;
        }
        // ---- stage V transposed (bf16 RNE), c folded in; packed b32 writes ----
        {
            const int p = t >> 4;    // 0..15 -> kk pair
            const int mm = t & 15;
#pragma unroll
            for (int g = 0; g < 2; ++g) {
                const int kka = 2 * p + 32 * g;
                const float ca = cp[k0 + kka], cb = cp[k0 + kka + 1];
                const float* va = vp + ((size_t)(h * LQ + k0 + kka)) * DH;
                const float* vb = va + DH;
#pragma unroll
                for (int dd = 0; dd < 4; ++dd) {
                    const int d = mm + 16 * dd;
                    const unsigned short ha = bf_rne(va[d] * ca);
                    const unsigned short hb = bf_rne(vb[d] * cb);
                    *(unsigned int*)&sh_vhi[d * 72 + kka] = (unsigned int)ha | ((unsigned int)hb << 16);
                }
            }
        }
        // ---- per-k folded bias coefficients ----
        if (t < 64) {
            const int kg = k0 + t;
            const float* sc_ = dksp + (size_t)kg * 8;   // [2][4] top then bottom
            const float* tp  = dktp + (size_t)kg * 3;
            const float* bt  = dkbp + (size_t)kg * 3;
            float cw = 0.f, cb2 = 0.f;
#pragma unroll
            for (int f = 0; f < 3; ++f) {
                const float stf = sc_[f], sbf = sc_[4 + f];
                const float A  = stf + sbf;
                const float Bv = tp[f] * stf + bt[f] * sbf;
                sh_meta[t * 13 + f]     = A * Ww[f];
                sh_meta[t * 13 + 4 + f] = A * Wb[f];
                cw  -= Bv * Ww[f];
                cb2 -= Bv * Wb[f];
            }
            sh_meta[t * 13 + 3]  = cw;              sh_meta[t * 13 + 7]  = cb2;
            sh_meta[t * 13 + 8]  = sc_[3] * Ww[3];  sh_meta[t * 13 + 9]  = sc_[7] * Ww[3];
            sh_meta[t * 13 + 10] = sc_[3] * Wb[3];  sh_meta[t * 13 + 11] = sc_[7] * Wb[3];
        }
        __syncthreads();

        // ---- prefetch rel features (hidden behind MFMA phase) ----
        float rt_[4][4], rb_[4][4];
#pragma unroll
        for (int r = 0; r < 4; ++r) {
            const size_t q = (size_t)(q0 + w16 + quad * 4 + r);
#pragma unroll
            for (int nt = 0; nt < 4; ++nt) {
                rt_[nt][r] = rtp[q * LQ + k0 + nt * 16 + m];
                rb_[nt][r] = rbp[q * LQ + k0 + nt * 16 + m];
            }
        }

        // ---- QK^T: 3-term split-bf16 MFMA (scale pre-folded into Q) ----
        floatx4 sc[4] = {zf, zf, zf, zf};
#pragma unroll
        for (int nt = 0; nt < 4; ++nt) {
#pragma unroll
            for (int kc = 0; kc < 2; ++kc) {
                const int kb = (nt * 16 + m) * 72 + kc * 32 + quad * 8;
                bf16x8 bh = *(const bf16x8*)&sh_khi[kb];
                bf16x8 bl = *(const bf16x8*)&sh_klo[kb];
                sc[nt] = MFMA16(aqh[kc], bh, sc[nt]);
                sc[nt] = MFMA16(aql[kc], bh, sc[nt]);
                sc[nt] = MFMA16(aqh[kc], bl, sc[nt]);
            }
        }
        __syncthreads();   // all waves done with K-lo -> reuse as ebf

        // ---- epilogue: gate + bias + exp; P->LDS (bf16, A-layout rows) ----
        unsigned short* ebf = sh_klo;
#pragma unroll
        for (int nt = 0; nt < 4; ++nt) {
            const int kcol = nt * 16 + m;
            const float m0 = sh_meta[kcol * 13 + 0],  m1 = sh_meta[kcol * 13 + 1];
            const float m2 = sh_meta[kcol * 13 + 2],  m3 = sh_meta[kcol * 13 + 3];
            const float m4 = sh_meta[kcol * 13 + 4],  m5 = sh_meta[kcol * 13 + 5];
            const float m6 = sh_meta[kcol * 13 + 6],  m7 = sh_meta[kcol * 13 + 7];
            const float m8 = sh_meta[kcol * 13 + 8],  m9 = sh_meta[kcol * 13 + 9];
            const float mA = sh_meta[kcol * 13 + 10], mB = sh_meta[kcol * 13 + 11];
#pragma unroll
            for (int r = 0; r < 4; ++r) {
                float ww = fmaf(dq0[r], m0, m3); ww = fmaf(dq1[r], m1, ww); ww = fmaf(dq2[r], m2, ww);
                ww = fmaf(rt_[nt][r], m8, ww);   ww = fmaf(rb_[nt][r], m9, ww);
                float bb = fmaf(dq0[r], m4, m7); bb = fmaf(dq1[r], m5, bb); bb = fmaf(dq2[r], m6, bb);
                bb = fmaf(rt_[nt][r], mA, bb);   bb = fmaf(rb_[nt][r], mB, bb);
                // softplus(ww) = ln(1 + 2^(ww*log2e)); safe for |ww| << 88 (data is O(10))
                const float wg = __logf(1.0f + __builtin_amdgcn_exp2f(ww * 1.44269504f));
                const float sv = fmaf(sc[nt][r], wg, bb);
                // e = exp(sv - 8): constant shift cancels in normalization
                const float e  = __builtin_amdgcn_exp2f(fmaf(sv, 1.44269504f, -11.5415603f));
                lpart[r] += e;
                if (!FAST)
                    probp[((size_t)(h * LQ + q0 + w16 + quad * 4 + r)) * LQ + k0 + kcol] = e;
                ebf[(w16 + quad * 4 + r) * 72 + kcol] = bf_rne(e);
            }
        }

        // ---- PV: bf16 P x bf16 V (own-wave rows; no barrier needed before reads) ----
        bf16x8 ap0 = *(const bf16x8*)&ebf[(w16 + m) * 72 + quad * 8];
        bf16x8 ap1 = *(const bf16x8*)&ebf[(w16 + m) * 72 + 32 + quad * 8];
#pragma unroll
        for (int nt = 0; nt < 4; ++nt) {
            const int vb = (nt * 16 + m) * 72 + quad * 8;
            bf16x8 bh0 = *(const bf16x8*)&sh_vhi[vb];
            bf16x8 bh1 = *(const bf16x8*)&sh_vhi[vb + 32];
            pacc[nt] = MFMA16(ap0, bh0, pacc[nt]);
            pacc[nt] = MFMA16(ap1, bh1, pacc[nt]);
        }

        // ---- FAST: dump own-wave ebf rows to global as bf16 (coalesced b128) ----
        if (FAST) {
            const int rrow = w16 + (lane >> 2);   // 16 rows/wave, 4 lanes per row
#pragma unroll
            for (int it = 0; it < 2; ++it) {
                const int cc = (lane & 3) + it * 4;  // 8 x ushort8 per 64-col row
                ushort8 v = *(const ushort8*)&ebf[rrow * 72 + cc * 8];
                *(ushort8*)(ews + ((size_t)(h * LQ + q0 + rrow)) * LQ + k0 + cc * 8) = v;
            }
        }
        __syncthreads();   // ebf/vT consumed before next staging
    }

    // ---- row-sum partials: reduce over the 16 m-lanes ----
#pragma unroll
    for (int off = 1; off < 16; off <<= 1) {
#pragma unroll
        for (int r = 0; r < 4; ++r) lpart[r] += __shfl_xor(lpart[r], off, 64);
    }
    if (m == 0) {
#pragma unroll
        for (int r = 0; r < 4; ++r)
            lws[quar * (NH * LQ) + h * LQ + q0 + w16 + quad * 4 + r] = lpart[r];
    }
    // ---- PV partials to ws ----
#pragma unroll
    for (int nt = 0; nt < 4; ++nt) {
#pragma unroll
        for (int r = 0; r < 4; ++r) {
            const size_t row = (size_t)(h * LQ + q0 + w16 + quad * 4 + r);
            pvws[(size_t)quar * (NH * LQ * DH) + row * DH + nt * 16 + m] = pacc[nt][r];
        }
    }
}

// out = (pv0+pv1+pv2+pv3) / (l0+l1+l2+l3)
__global__ void combine_kernel(const float* __restrict__ pvws, const float* __restrict__ lws,
                               float* __restrict__ outp)
{
    const int idx4 = blockIdx.x * 256 + threadIdx.x;   // 0..262143
    const int row  = idx4 >> 4;
    const int d4   = (idx4 & 15) * 4;
    const size_t stride = (size_t)NH * LQ * DH;
    floatx4 s = {0.f, 0.f, 0.f, 0.f};
    float l = 0.f;
#pragma unroll
    for (int qr = 0; qr < 4; ++qr) {
        s += *(const floatx4*)(pvws + qr * stride + (size_t)row * DH + d4);
        l += lws[qr * (NH * LQ) + row];
    }
    const float rl = 1.0f / l;
    *(floatx4*)(outp + (size_t)row * DH + d4) = s * rl;
}

// FAST path: probs[row][k] = bf16(e)[row][k] * c[k] / l[row].
// Lane-CONTIGUOUS addressing: thread t handles k=t*4 and k=1024+t*4 so each
// wave's loads are one 2KB span (b64/lane) and stores one 4KB span (b128/lane).
// R5's k=t*8 layout gave 32B lane stride -> half-filled cachelines + NT bypass
// -> DRAM RMW at ~1 TB/s (finalize was ~180us of the 322us total).
__global__ __launch_bounds__(256) void finalize_kernel(const unsigned short* __restrict__ ews,
                                                       const float* __restrict__ cp,
                                                       const float* __restrict__ lws,
                                                       float* __restrict__ probp)
{
    const int row = blockIdx.x;                        // 16384 rows
    const int t   = threadIdx.x;
    float l = 0.f;
#pragma unroll
    for (int qr = 0; qr < 4; ++qr) l += lws[qr * (NH * LQ) + row];
    const float rl = 1.0f / l;

    const size_t base = (size_t)row * LQ;
#pragma unroll
    for (int g = 0; g < 2; ++g) {
        const int k = g * 1024 + t * 4;
        const ushort4v e = *(const ushort4v*)(ews + base + k);
        const floatx4 c = *(const floatx4*)(cp + k);
        floatx4 o;
#pragma unroll
        for (int j = 0; j < 4; ++j) o[j] = bf_up(e[j]) * c[j] * rl;
        __builtin_nontemporal_store(o, (floatx4*)(probp + base + k));
    }
}

// Fallback: probs RMW in place (e stored f32 by attn_main<false>)
__global__ __launch_bounds__(256) void norm_kernel(float* __restrict__ probp,
                                                   const float* __restrict__ cp,
                                                   const float* __restrict__ lws)
{
    const int r0 = blockIdx.x * 4;
    const int t  = threadIdx.x;
    const floatx4 c0 = *(const floatx4*)(cp + t * 4);
    const floatx4 c1 = *(const floatx4*)(cp + (t + 256) * 4);
#pragma unroll
    for (int r = 0; r < 4; ++r) {
        const int row = r0 + r;
        float l = 0.f;
#pragma unroll
        for (int qr = 0; qr < 4; ++qr) l += lws[qr * (NH * LQ) + row];
        const float rl = 1.0f / l;
        float* p = probp + (size_t)row * LQ;
        floatx4 x0 = *(const floatx4*)(p + t * 4);
        floatx4 x1 = *(const floatx4*)(p + (t + 256) * 4);
        x0 = x0 * c0 * rl;
        x1 = x1 * c1 * rl;
        __builtin_nontemporal_store(x0, (floatx4*)(p + t * 4));
        __builtin_nontemporal_store(x1, (floatx4*)(p + (t + 256) * 4));
    }
}

extern "C" void kernel_launch(void* const* d_in, const int* in_sizes, int n_in,
                              void* d_out, int out_size, void* d_ws, size_t ws_size,
                              hipStream_t stream)
{
    (void)in_sizes; (void)n_in; (void)out_size;
    const float* qp   = (const float*)d_in[0];
    const float* kp   = (const float*)d_in[1];
    const float* vp   = (const float*)d_in[2];
    const float* cp   = (const float*)d_in[3];
    const float* dqp  = (const float*)d_in[4];
    const float* dktp = (const float*)d_in[5];
    const float* dkbp = (const float*)d_in[6];
    const float* dksp = (const float*)d_in[7];
    const float* rtp  = (const float*)d_in[8];
    const float* rbp  = (const float*)d_in[9];
    const float* Wwp  = (const float*)d_in[10];
    const float* Wbp  = (const float*)d_in[11];

    float* outp  = (float*)d_out;                            // [1,8,2048,64]
    float* probp = (float*)d_out + (size_t)NH * LQ * DH;     // [1,8,2048,2048]

    float* lws  = (float*)d_ws;                              // [4][16384]        = 256 KB
    float* pvws = (float*)d_ws + 4 * (NH * LQ);              // [4][16384*64] f32 = 16 MB
    unsigned short* ews = (unsigned short*)(pvws + (size_t)4 * NH * LQ * DH);  // 64 MB bf16

    const size_t need = (size_t)4 * NH * LQ * 4
                      + (size_t)4 * NH * LQ * DH * 4
                      + (size_t)NH * LQ * LQ * 2;
    const bool fast = ws_size >= need;

    if (fast) {
        attn_main<true><<<dim3(1024), dim3(256), 0, stream>>>(
            qp, kp, vp, cp, dqp, dktp, dkbp, dksp, rtp, rbp, Wwp, Wbp, probp, lws, pvws, ews);
        combine_kernel<<<dim3(1024), dim3(256), 0, stream>>>(pvws, lws, outp);
        finalize_kernel<<<dim3(16384), dim3(256), 0, stream>>>(ews, cp, lws, probp);
    } else {
        attn_main<false><<<dim3(1024), dim3(256), 0, stream>>>(
            qp, kp, vp, cp, dqp, dktp, dkbp, dksp, rtp, rbp, Wwp, Wbp, probp, lws, pvws, ews);
        combine_kernel<<<dim3(1024), dim3(256), 0, stream>>>(pvws, lws, outp);
        norm_kernel<<<dim3(4096), dim3(256), 0, stream>>>(probp, cp, lws);
    }
}